// Round 2
// baseline (2820.164 us; speedup 1.0000x reference)
//
#include <hip/hip_runtime.h>

#define NN 100000
#define NE 600000
#define DIM 128
#define NREL 8
#define LN_EPS 1e-5f

// ---------------------------------------------------------------------------
// deg[r][n] = number of edges of type r with dst n (as float)
__global__ __launch_bounds__(256) void deg_kernel(const int* __restrict__ etype,
                                                  const int* __restrict__ dst,
                                                  float* __restrict__ deg) {
    int e = blockIdx.x * 256 + threadIdx.x;
    if (e < NE) {
        int t = etype[e];
        int d = dst[e];
        atomicAdd(&deg[t * NN + d], 1.0f);
    }
}

// ---------------------------------------------------------------------------
// acc[dst] += h[src] for edges of type `rel`. 32 threads per edge, 4 floats each.
__global__ __launch_bounds__(256) void scatter_kernel(const float* __restrict__ h,
                                                      const int* __restrict__ src,
                                                      const int* __restrict__ dst,
                                                      const int* __restrict__ etype,
                                                      float* __restrict__ acc, int rel) {
    int g = blockIdx.x * 256 + threadIdx.x;
    int e = g >> 5;          // edge index
    int c = (g & 31) * 4;    // feature chunk
    if (e < NE && etype[e] == rel) {
        int s = src[e], d = dst[e];
        const float4 v = *reinterpret_cast<const float4*>(h + (size_t)s * DIM + c);
        float* p = acc + (size_t)d * DIM + c;
        atomicAdd(p + 0, v.x);
        atomicAdd(p + 1, v.y);
        atomicAdd(p + 2, v.z);
        atomicAdd(p + 3, v.w);
    }
}

// ---------------------------------------------------------------------------
// out[n][i] (+)= scale_n * sum_j X[n][j] * W[i][j]  (+ bias[i])
// scale_n = 1/max(dg[n],1) if dg != nullptr else 1.
// Block: 256 threads -> 64 rows x 128 cols. Thread: 2 rows x 16 cols.
__global__ __launch_bounds__(256) void gemm_kernel(const float* __restrict__ X,
                                                   const float* __restrict__ W,
                                                   const float* __restrict__ bias,
                                                   const float* __restrict__ dg,
                                                   float* __restrict__ out,
                                                   int accumulate) {
    __shared__ float Wt[DIM][DIM];  // Wt[j][i] = W[i][j]
    for (int idx = threadIdx.x; idx < DIM * DIM; idx += 256) {
        int j = idx >> 7, i = idx & 127;
        Wt[j][i] = W[i * DIM + j];
    }
    __syncthreads();

    int tg = threadIdx.x & 7;    // col group (x16)
    int tr = threadIdx.x >> 3;   // row pair (x2)
    int rowA = blockIdx.x * 64 + tr * 2;
    int rowB = rowA + 1;
    int cb = tg * 16;
    int rA = rowA < NN ? rowA : NN - 1;
    int rB = rowB < NN ? rowB : NN - 1;
    const float* xA = X + (size_t)rA * DIM;
    const float* xB = X + (size_t)rB * DIM;

    float sA[16], sB[16];
#pragma unroll
    for (int c = 0; c < 16; ++c) { sA[c] = 0.f; sB[c] = 0.f; }

    for (int j = 0; j < DIM; j += 4) {
        float4 a = *reinterpret_cast<const float4*>(xA + j);
        float4 b = *reinterpret_cast<const float4*>(xB + j);
#pragma unroll
        for (int jj = 0; jj < 4; ++jj) {
            float av = (&a.x)[jj];
            float bv = (&b.x)[jj];
            const float* wr = &Wt[j + jj][cb];
#pragma unroll
            for (int c = 0; c < 16; c += 4) {
                float4 w = *reinterpret_cast<const float4*>(wr + c);
                sA[c + 0] += av * w.x; sA[c + 1] += av * w.y;
                sA[c + 2] += av * w.z; sA[c + 3] += av * w.w;
                sB[c + 0] += bv * w.x; sB[c + 1] += bv * w.y;
                sB[c + 2] += bv * w.z; sB[c + 3] += bv * w.w;
            }
        }
    }

    float scaleA = 1.f, scaleB = 1.f;
    if (dg) {
        scaleA = 1.f / fmaxf(dg[rA], 1.f);
        scaleB = 1.f / fmaxf(dg[rB], 1.f);
    }
    if (rowA < NN) {
        float* o = out + (size_t)rowA * DIM + cb;
#pragma unroll
        for (int c = 0; c < 16; ++c) {
            float v = sA[c] * scaleA + (bias ? bias[cb + c] : 0.f);
            if (accumulate) v += o[c];
            o[c] = v;
        }
    }
    if (rowB < NN) {
        float* o = out + (size_t)rowB * DIM + cb;
#pragma unroll
        for (int c = 0; c < 16; ++c) {
            float v = sB[c] * scaleB + (bias ? bias[cb + c] : 0.f);
            if (accumulate) v += o[c];
            o[c] = v;
        }
    }
}

// ---------------------------------------------------------------------------
// in-place relu + layernorm. One 64-lane wave per row (2 floats/lane).
__global__ __launch_bounds__(256) void ln_kernel(float* __restrict__ out,
                                                 const float* __restrict__ gamma,
                                                 const float* __restrict__ beta) {
    int row = blockIdx.x * 4 + (threadIdx.x >> 6);
    int lane = threadIdx.x & 63;
    float* orow = out + (size_t)row * DIM;
    float2 v = *reinterpret_cast<const float2*>(orow + lane * 2);
    v.x = fmaxf(v.x, 0.f);
    v.y = fmaxf(v.y, 0.f);
    float sum = v.x + v.y;
    float sumsq = v.x * v.x + v.y * v.y;
#pragma unroll
    for (int off = 32; off; off >>= 1) {
        sum += __shfl_xor(sum, off);
        sumsq += __shfl_xor(sumsq, off);
    }
    float mean = sum * (1.f / DIM);
    float var = sumsq * (1.f / DIM) - mean * mean;
    float r = rsqrtf(var + LN_EPS);
    float2 g = *reinterpret_cast<const float2*>(gamma + lane * 2);
    float2 b = *reinterpret_cast<const float2*>(beta + lane * 2);
    v.x = (v.x - mean) * r * g.x + b.x;
    v.y = (v.y - mean) * r * g.y + b.y;
    *reinterpret_cast<float2*>(orow + lane * 2) = v;
}

// ---------------------------------------------------------------------------
extern "C" void kernel_launch(void* const* d_in, const int* in_sizes, int n_in,
                              void* d_out, int out_size, void* d_ws, size_t ws_size,
                              hipStream_t stream) {
    const float* h      = (const float*)d_in[0];
    const int*   eidx   = (const int*)d_in[1];   // [2, NE], int64 -> int32 by harness
    const int*   etype  = (const int*)d_in[2];   // [NE]
    const float* W_self = (const float*)d_in[3]; // [128,128]
    const float* b_self = (const float*)d_in[4]; // [128]
    const float* W_rel  = (const float*)d_in[5]; // [8,128,128]
    const float* gamma  = (const float*)d_in[6];
    const float* beta   = (const float*)d_in[7];
    float* out = (float*)d_out;                  // [NN,128] fp32

    const int* src = eidx;
    const int* dst = eidx + NE;

    // ws layout: acc [NN*DIM] f32 (51.2 MB) + deg [NREL*NN] f32 (3.2 MB)
    float* acc = (float*)d_ws;
    float* deg = acc + (size_t)NN * DIM;

    hipMemsetAsync(deg, 0, sizeof(float) * NREL * NN, stream);
    deg_kernel<<<(NE + 255) / 256, 256, 0, stream>>>(etype, dst, deg);

    // out = h @ W_self^T + b_self
    gemm_kernel<<<(NN + 63) / 64, 256, 0, stream>>>(h, W_self, b_self, nullptr, out, 0);

    for (int r = 0; r < NREL; ++r) {
        hipMemsetAsync(acc, 0, sizeof(float) * NN * DIM, stream);
        scatter_kernel<<<(NE * 32) / 256, 256, 0, stream>>>(h, src, dst, etype, acc, r);
        gemm_kernel<<<(NN + 63) / 64, 256, 0, stream>>>(
            acc, W_rel + (size_t)r * DIM * DIM, nullptr, deg + (size_t)r * NN, out, 1);
    }

    ln_kernel<<<NN / 4, 256, 0, stream>>>(out, gamma, beta);
}

// Round 4
// 2375.869 us; speedup vs baseline: 1.1870x; 1.1870x over previous
//
#include <hip/hip_runtime.h>

#define NN 100000
#define NE 600000
#define DIM 128
#define NREL 8
#define LN_EPS 1e-5f

typedef __attribute__((ext_vector_type(8))) short short8;
typedef __attribute__((ext_vector_type(4))) float f32x4;

// RNE float -> bf16 (bit pattern in low 16)
static __device__ __forceinline__ short f2bf(float x) {
    unsigned int u = __float_as_uint(x);
    u = (u + 0x7FFFu + ((u >> 16) & 1u)) >> 16;
    return (short)u;
}

// ---------------------------------------------------------------------------
// Pass 1: deg[r][n] counts + per-bucket edge counts (LDS histogram).
// meta: [0..15]=cnt, [16..32]=off, [33..48]=cur
__global__ __launch_bounds__(256) void count_kernel(const int* __restrict__ dstA,
                                                    const int* __restrict__ etype,
                                                    float* __restrict__ deg,
                                                    unsigned int* __restrict__ meta,
                                                    int CH) {
    __shared__ unsigned int hcnt[16];
    if (threadIdx.x < 16) hcnt[threadIdx.x] = 0;
    __syncthreads();
    int e = blockIdx.x * 256 + threadIdx.x;
    if (e < NE) {
        int d = dstA[e], t = etype[e];
        atomicAdd(&deg[(size_t)t * NN + d], 1.0f);
        atomicAdd(&hcnt[(unsigned int)d / (unsigned int)CH], 1u);
    }
    __syncthreads();
    if (threadIdx.x < 16 && hcnt[threadIdx.x])
        atomicAdd(&meta[threadIdx.x], hcnt[threadIdx.x]);
}

__global__ void scan_kernel(unsigned int* __restrict__ meta, int NB) {
    if (threadIdx.x == 0 && blockIdx.x == 0) {
        unsigned int o = 0;
        meta[16] = 0;
        for (int b = 0; b < NB; ++b) { o += meta[b]; meta[16 + b + 1] = o; }
        for (int b = 0; b < NB; ++b) meta[33 + b] = meta[16 + b];
    }
}

// Pass 2: fill ebuf sorted by bucket; wave-aggregated cursor atomics.
__global__ __launch_bounds__(256) void fill_kernel(const int* __restrict__ srcA,
                                                   const int* __restrict__ dstA,
                                                   const int* __restrict__ etype,
                                                   unsigned int* __restrict__ meta,
                                                   uint2* __restrict__ ebuf,
                                                   int CH, int NB) {
    int e = blockIdx.x * 256 + threadIdx.x;
    unsigned int b = 0xFFFFFFFFu;
    uint2 rec = make_uint2(0u, 0u);
    if (e < NE) {
        int d = dstA[e], s = srcA[e], t = etype[e];
        b = (unsigned int)d / (unsigned int)CH;
        rec = make_uint2((unsigned int)s, ((unsigned int)d << 3) | (unsigned int)t);
    }
    int lane = threadIdx.x & 63;
    for (unsigned int bb = 0; bb < (unsigned int)NB; ++bb) {
        unsigned long long m = __ballot(b == bb);
        if (!m) continue;
        int leader = __ffsll((unsigned long long)m) - 1;
        unsigned int base = 0;
        if (lane == leader) base = atomicAdd(&meta[33 + bb], (unsigned int)__popcll(m));
        base = __shfl(base, leader);
        if (b == bb) {
            unsigned int rank = (unsigned int)__popcll(m & ((1ull << lane) - 1ull));
            ebuf[base + rank] = rec;
        }
    }
}

// ---------------------------------------------------------------------------
// Dense scatter for one bucket: acc8[dst-n0][rel][:] += h[src][:]
__global__ __launch_bounds__(256) void scatter_kernel(float* __restrict__ acc8,
                                                      const float* __restrict__ h,
                                                      const uint2* __restrict__ ebuf,
                                                      const unsigned int* __restrict__ meta,
                                                      int b, int n0) {
    unsigned int beg = meta[16 + b], end = meta[16 + b + 1];
    unsigned int items = (end - beg) << 5;  // 32 lanes per edge
    for (unsigned int i = blockIdx.x * 256 + threadIdx.x; i < items;
         i += gridDim.x * 256) {
        uint2 ed = ebuf[beg + (i >> 5)];
        int c = (int)(i & 31) << 2;
        int s = (int)ed.x;
        int dl = (int)(ed.y >> 3) - n0;
        int r = (int)(ed.y & 7u);
        const float4 v = *reinterpret_cast<const float4*>(h + (size_t)s * DIM + c);
        float* p = acc8 + ((size_t)dl * NREL + r) * DIM + c;
        atomicAdd(p + 0, v.x);
        atomicAdd(p + 1, v.y);
        atomicAdd(p + 2, v.z);
        atomicAdd(p + 3, v.w);
    }
}

// ---------------------------------------------------------------------------
// Fused: out[n] = LN(ReLU(h[n]@Ws^T + b + sum_r (acc8[n][r]/deg)@Wr^T))
// K = 1152 = 9 segments of 128. Block = 64 rows, 4 waves (each 16 rows x 128 cols).
// W tile (128 feat x 64 k) staged in LDS as bf16 with XOR-swizzled k-groups.
__global__ __launch_bounds__(256) void fused_gemm_kernel(
    float* __restrict__ out, const float* __restrict__ h,
    const float* __restrict__ acc8, const float* __restrict__ deg,
    const float* __restrict__ W_self, const float* __restrict__ W_rel,
    const float* __restrict__ b_self, const float* __restrict__ gamma,
    const float* __restrict__ beta, int n0) {
    __shared__ short Wlds[DIM * 64];  // 16 KB bf16, [feat][kgroup^swz][8]

    const int t = threadIdx.x;
    const int w = t >> 6, l = t & 63;
    const int l15 = l & 15, lq = l >> 4;
    const int brow = blockIdx.x * 64 + w * 16;  // wave's local row base

    f32x4 acc[8];
#pragma unroll
    for (int i = 0; i < 8; ++i) acc[i] = (f32x4)(0.f);

    const int nloc = brow + l15;  // A-operand row (local)
    const int gn = n0 + nloc;
    const int gcl = gn < NN ? gn : NN - 1;

    const int sq = t & 3;  // staging k-quarter

    for (int s = 0; s < 18; ++s) {
        const int kbase = s * 64;
        const int seg = kbase >> 7;  // 0..8
        const int kk = kbase & 127;  // 0 or 64

        // ---- stage W segment tile -> LDS (f32 -> bf16, swizzled) ----
        // 128 features x 64 k. 256 threads x 2 halves: thread covers
        // feature sf = (t>>2) + half*64, k-quarter sq*16.
#pragma unroll
        for (int half = 0; half < 2; ++half) {
            const int sf = (t >> 2) + half * 64;
            const float* wsrc =
                (seg == 0 ? W_self + (size_t)sf * DIM
                          : W_rel + ((size_t)(seg - 1) * DIM + sf) * DIM) +
                kk + sq * 16;
            float4 w0 = reinterpret_cast<const float4*>(wsrc)[0];
            float4 w1 = reinterpret_cast<const float4*>(wsrc)[1];
            float4 w2 = reinterpret_cast<const float4*>(wsrc)[2];
            float4 w3 = reinterpret_cast<const float4*>(wsrc)[3];
            short8 lo, hi;
            lo[0] = f2bf(w0.x); lo[1] = f2bf(w0.y); lo[2] = f2bf(w0.z); lo[3] = f2bf(w0.w);
            lo[4] = f2bf(w1.x); lo[5] = f2bf(w1.y); lo[6] = f2bf(w1.z); lo[7] = f2bf(w1.w);
            hi[0] = f2bf(w2.x); hi[1] = f2bf(w2.y); hi[2] = f2bf(w2.z); hi[3] = f2bf(w2.w);
            hi[4] = f2bf(w3.x); hi[5] = f2bf(w3.y); hi[6] = f2bf(w3.z); hi[7] = f2bf(w3.w);
            int g0 = sq * 2;
            int gp0 = g0 ^ (sf & 7), gp1 = (g0 + 1) ^ (sf & 7);
            *reinterpret_cast<short8*>(&Wlds[sf * 64 + gp0 * 8]) = lo;
            *reinterpret_cast<short8*>(&Wlds[sf * 64 + gp1 * 8]) = hi;
        }
        __syncthreads();

        // ---- A source + scale for this segment ----
        float sc = 1.f;
        const float* abase;
        if (seg == 0) {
            abase = h + (size_t)gcl * DIM + kk;
        } else {
            abase = acc8 + ((size_t)nloc * NREL + (seg - 1)) * DIM + kk;
            sc = 1.f / fmaxf(deg[(size_t)(seg - 1) * NN + gcl], 1.f);
        }

#pragma unroll
        for (int ks = 0; ks < 2; ++ks) {
            const float4* pa =
                reinterpret_cast<const float4*>(abase + ks * 32 + lq * 8);
            float4 a0 = pa[0], a1 = pa[1];
            short8 af;
            af[0] = f2bf(a0.x * sc); af[1] = f2bf(a0.y * sc);
            af[2] = f2bf(a0.z * sc); af[3] = f2bf(a0.w * sc);
            af[4] = f2bf(a1.x * sc); af[5] = f2bf(a1.y * sc);
            af[6] = f2bf(a1.z * sc); af[7] = f2bf(a1.w * sc);
#pragma unroll
            for (int tt = 0; tt < 8; ++tt) {
                int feat = tt * 16 + l15;
                int gp = (ks * 4 + lq) ^ (l & 7);
                short8 bf_ = *reinterpret_cast<const short8*>(&Wlds[feat * 64 + gp * 8]);
                acc[tt] = __builtin_amdgcn_mfma_f32_16x16x32_bf16(af, bf_, acc[tt], 0, 0, 0);
            }
        }
        __syncthreads();
    }

    // ---- fused bias + ReLU + LayerNorm epilogue ----
    float bias[8], gm[8], bt[8];
#pragma unroll
    for (int tt = 0; tt < 8; ++tt) {
        bias[tt] = b_self[tt * 16 + l15];
        gm[tt] = gamma[tt * 16 + l15];
        bt[tt] = beta[tt * 16 + l15];
    }
    float s1[4] = {0, 0, 0, 0}, s2[4] = {0, 0, 0, 0};
#pragma unroll
    for (int q = 0; q < 4; ++q)
#pragma unroll
        for (int tt = 0; tt < 8; ++tt) {
            float v = fmaxf(acc[tt][q] + bias[tt], 0.f);
            acc[tt][q] = v;
            s1[q] += v;
            s2[q] += v * v;
        }
#pragma unroll
    for (int m = 1; m < 16; m <<= 1) {
#pragma unroll
        for (int q = 0; q < 4; ++q) {
            s1[q] += __shfl_xor(s1[q], m);
            s2[q] += __shfl_xor(s2[q], m);
        }
    }
#pragma unroll
    for (int q = 0; q < 4; ++q) {
        int grow = n0 + brow + lq * 4 + q;
        if (grow < NN) {
            float mean = s1[q] * (1.f / DIM);
            float var = s2[q] * (1.f / DIM) - mean * mean;
            float rst = rsqrtf(var + LN_EPS);
            float* orow = out + (size_t)grow * DIM;
#pragma unroll
            for (int tt = 0; tt < 8; ++tt)
                orow[tt * 16 + l15] = (acc[tt][q] - mean) * rst * gm[tt] + bt[tt];
        }
    }
}

// ---------------------------------------------------------------------------
extern "C" void kernel_launch(void* const* d_in, const int* in_sizes, int n_in,
                              void* d_out, int out_size, void* d_ws, size_t ws_size,
                              hipStream_t stream) {
    const float* h      = (const float*)d_in[0];
    const int*   eidx   = (const int*)d_in[1];
    const int*   etype  = (const int*)d_in[2];
    const float* W_self = (const float*)d_in[3];
    const float* b_self = (const float*)d_in[4];
    const float* W_rel  = (const float*)d_in[5];
    const float* gamma  = (const float*)d_in[6];
    const float* beta   = (const float*)d_in[7];
    float* out = (float*)d_out;

    const int* srcA = eidx;
    const int* dstA = eidx + NE;

    // ws layout: deg f32[8*NN] | meta u32[64] | ebuf uint2[NE] | acc8 f32[CH*8*128]
    float* deg = (float*)d_ws;
    unsigned int* meta = (unsigned int*)(deg + (size_t)NREL * NN);
    uint2* ebuf = (uint2*)(meta + 64);
    float* acc8 = (float*)(ebuf + NE);

    size_t fixed = (size_t)((char*)acc8 - (char*)d_ws);
    size_t avail = ws_size > fixed ? ws_size - fixed : 0;
    long chn = (long)(avail / ((size_t)NREL * DIM * 4));
    int CH = (int)(chn & ~63L);
    if (CH > 16384) CH = 16384;   // keep acc8 chunk L3-resident
    if (CH < 6272) CH = 6272;     // NB <= 16 (ws proven >= 54 MB in round 2)
    int NB = (NN + CH - 1) / CH;

    hipMemsetAsync(deg, 0, (size_t)NREL * NN * 4 + 64 * 4, stream);
    count_kernel<<<(NE + 255) / 256, 256, 0, stream>>>(dstA, etype, deg, meta, CH);
    scan_kernel<<<1, 64, 0, stream>>>(meta, NB);
    fill_kernel<<<(NE + 255) / 256, 256, 0, stream>>>(srcA, dstA, etype, meta, ebuf, CH, NB);

    for (int b = 0; b < NB; ++b) {
        int n0 = b * CH;
        hipMemsetAsync(acc8, 0, (size_t)CH * NREL * DIM * 4, stream);
        scatter_kernel<<<1024, 256, 0, stream>>>(acc8, h, ebuf, meta, b, n0);
        fused_gemm_kernel<<<CH / 64, 256, 0, stream>>>(out, h, acc8, deg, W_self,
                                                       W_rel, b_self, gamma, beta, n0);
    }
}

// Round 6
// 772.230 us; speedup vs baseline: 3.6520x; 3.0766x over previous
//
#include <hip/hip_runtime.h>

#define NN 100000
#define NE 600000
#define DIM 128
#define NREL 8
#define LN_EPS 1e-5f
#define NBUK 1563            // ceil(NN/64)
#define KEYS (NBUK * NREL)   // 12504

typedef __attribute__((ext_vector_type(8))) short short8;
typedef __attribute__((ext_vector_type(4))) float f32x4;

// RNE float -> bf16 (bit pattern in low 16)
static __device__ __forceinline__ short f2bf(float x) {
    unsigned int u = __float_as_uint(x);
    u = (u + 0x7FFFu + ((u >> 16) & 1u)) >> 16;
    return (short)u;
}

// ---------------------------------------------------------------------------
// deg[r][n] (float, for 1/deg scaling) + cnt[key] histogram.
// key = (dst>>6)*8 + rel -> 12504 keys spread over ~782 cache lines.
__global__ __launch_bounds__(256) void count_kernel(const int* __restrict__ dstA,
                                                    const int* __restrict__ etype,
                                                    float* __restrict__ deg,
                                                    unsigned* __restrict__ cnt) {
    int e = blockIdx.x * 256 + threadIdx.x;
    if (e < NE) {
        int d = dstA[e], t = etype[e];
        atomicAdd(&deg[(size_t)t * NN + d], 1.0f);
        atomicAdd(&cnt[(unsigned)(d >> 6) * NREL + (unsigned)t], 1u);
    }
}

// ---------------------------------------------------------------------------
// Single-block exclusive scan of cnt[KEYS] -> off[0..KEYS], cur = copy of off.
__global__ __launch_bounds__(1024) void scan_kernel(const unsigned* __restrict__ cnt,
                                                    unsigned* __restrict__ off,
                                                    unsigned* __restrict__ cur) {
    __shared__ unsigned buf[KEYS];   // 50 KB
    __shared__ unsigned wpart[16];
    int t = threadIdx.x;
    for (int i = t; i < KEYS; i += 1024) buf[i] = cnt[i];
    __syncthreads();
    const int L = 13;  // 1024*13 >= 12504
    int base = t * L;
    unsigned s = 0;
    for (int j = 0; j < L; ++j) { int i = base + j; if (i < KEYS) s += buf[i]; }
    unsigned incl = s;
    int lane = t & 63, wid = t >> 6;
    for (int d = 1; d < 64; d <<= 1) {
        unsigned v = __shfl_up(incl, d);
        if (lane >= d) incl += v;
    }
    if (lane == 63) wpart[wid] = incl;
    __syncthreads();
    unsigned wbase = 0;
    for (int q = 0; q < wid; ++q) wbase += wpart[q];
    unsigned run = wbase + incl - s;  // exclusive prefix of this thread's chunk
    for (int j = 0; j < L; ++j) {
        int i = base + j;
        if (i < KEYS) { unsigned c = buf[i]; off[i] = run; cur[i] = run; run += c; }
    }
    if (t == 1023) off[KEYS] = wbase + incl;  // = NE
}

// ---------------------------------------------------------------------------
// Fill sorted edge buffer. rec = src | dl<<17 | rel<<23 (src<2^17, dl<64).
__global__ __launch_bounds__(256) void fill_kernel(const int* __restrict__ srcA,
                                                   const int* __restrict__ dstA,
                                                   const int* __restrict__ etype,
                                                   unsigned* __restrict__ cur,
                                                   unsigned* __restrict__ ebuf) {
    int e = blockIdx.x * 256 + threadIdx.x;
    if (e < NE) {
        int d = dstA[e], s = srcA[e], t = etype[e];
        unsigned k = (unsigned)(d >> 6) * NREL + (unsigned)t;
        unsigned pos = atomicAdd(&cur[k], 1u);
        ebuf[pos] = (unsigned)s | ((unsigned)(d & 63) << 17) | ((unsigned)t << 23);
    }
}

// ---------------------------------------------------------------------------
// Fused per-bucket kernel: for 64 output rows, aggregate each relation's
// messages into a swizzled LDS A-tile (ds_add_f32, no global atomics), then
// MFMA with W_r staged in LDS; bias+ReLU+LayerNorm epilogue.
// LDS: Alds 32KB f32 (word = (row<<7) | (k ^ ((row&7)<<2))) + Wlds 32KB bf16.
__global__ __launch_bounds__(256) void fused_kernel(
    float* __restrict__ out, const float* __restrict__ h,
    const unsigned* __restrict__ ebuf, const unsigned* __restrict__ off,
    const float* __restrict__ deg,
    const float* __restrict__ W_self, const float* __restrict__ W_rel,
    const float* __restrict__ b_self, const float* __restrict__ gamma,
    const float* __restrict__ beta) {
    __shared__ float Alds[64 * DIM];   // 32 KB
    __shared__ short Wlds[DIM * DIM];  // 32 KB bf16: [feat][(kh*8 + (g ^ (feat&7)))*8]

    const int t = threadIdx.x;
    const int w = t >> 6, l = t & 63;
    const int l15 = l & 15, lq = l >> 4;
    const int b = blockIdx.x;
    const int rl = w * 16 + l15;        // local A-row this lane supplies
    const int gn = b * 64 + rl;
    const int gcl = gn < NN ? gn : NN - 1;
    const int hw = t >> 5;              // half-wave 0..7
    const int j32 = t & 31;

    f32x4 acc[8];
#pragma unroll
    for (int i = 0; i < 8; ++i) acc[i] = (f32x4)(0.f);

    const float* hrow = h + (size_t)gcl * DIM;
    const int swr = (rl & 7) << 2;

    for (int seg = 0; seg < 9; ++seg) {
        // ---- stage W_seg (128 feat x 128 k) f32 -> bf16, swizzled ----
        {
            const int sq = t & 3;
#pragma unroll
            for (int kh = 0; kh < 2; ++kh)
#pragma unroll
                for (int half = 0; half < 2; ++half) {
                    const int sf = (t >> 2) + half * 64;
                    const float* wsrc =
                        (seg == 0 ? W_self + (size_t)sf * DIM
                                  : W_rel + ((size_t)(seg - 1) * DIM + sf) * DIM) +
                        kh * 64 + sq * 16;
                    float4 w0 = reinterpret_cast<const float4*>(wsrc)[0];
                    float4 w1 = reinterpret_cast<const float4*>(wsrc)[1];
                    float4 w2 = reinterpret_cast<const float4*>(wsrc)[2];
                    float4 w3 = reinterpret_cast<const float4*>(wsrc)[3];
                    short8 lo, hi;
                    lo[0] = f2bf(w0.x); lo[1] = f2bf(w0.y); lo[2] = f2bf(w0.z); lo[3] = f2bf(w0.w);
                    lo[4] = f2bf(w1.x); lo[5] = f2bf(w1.y); lo[6] = f2bf(w1.z); lo[7] = f2bf(w1.w);
                    hi[0] = f2bf(w2.x); hi[1] = f2bf(w2.y); hi[2] = f2bf(w2.z); hi[3] = f2bf(w2.w);
                    hi[4] = f2bf(w3.x); hi[5] = f2bf(w3.y); hi[6] = f2bf(w3.z); hi[7] = f2bf(w3.w);
                    int g0 = sq * 2;
                    int gp0 = kh * 8 + (g0 ^ (sf & 7));
                    int gp1 = kh * 8 + ((g0 + 1) ^ (sf & 7));
                    *reinterpret_cast<short8*>(&Wlds[sf * DIM + gp0 * 8]) = lo;
                    *reinterpret_cast<short8*>(&Wlds[sf * DIM + gp1 * 8]) = hi;
                }
        }
        // ---- zero A tile ----
        if (seg >= 1) {
            float4* A4 = reinterpret_cast<float4*>(Alds);
            for (int i = t; i < 64 * DIM / 4; i += 256)
                A4[i] = make_float4(0.f, 0.f, 0.f, 0.f);
        }
        __syncthreads();
        // ---- aggregate edges of rel seg-1 into Alds (half-wave per edge) ----
        if (seg >= 1) {
            const int r = seg - 1;
            unsigned o0 = off[(unsigned)b * NREL + r];
            unsigned o1 = off[(unsigned)b * NREL + r + 1];
            for (unsigned u = o0 + hw; u < o1; u += 8) {
                unsigned rec = ebuf[u];
                int s = (int)(rec & 0x1FFFFu);
                int dl = (int)((rec >> 17) & 63u);
                float4 v = reinterpret_cast<const float4*>(h + (size_t)s * DIM)[j32];
                int sw = (dl & 7) << 2;
                int wb = (dl << 7) | ((j32 * 4) ^ sw);
                atomicAdd(&Alds[wb + 0], v.x);
                atomicAdd(&Alds[wb + 1], v.y);
                atomicAdd(&Alds[wb + 2], v.z);
                atomicAdd(&Alds[wb + 3], v.w);
            }
            __syncthreads();
        }
        // ---- MFMA over this 128-K segment ----
        float sc = 1.f;
        if (seg >= 1) sc = 1.f / fmaxf(deg[(size_t)(seg - 1) * NN + gcl], 1.f);
#pragma unroll
        for (int kh = 0; kh < 2; ++kh) {
#pragma unroll
            for (int ks = 0; ks < 2; ++ks) {
                int k0 = kh * 64 + ks * 32 + lq * 8;
                float4 a0, a1;
                if (seg == 0) {
                    const float4* pa = reinterpret_cast<const float4*>(hrow + k0);
                    a0 = pa[0];
                    a1 = pa[1];
                } else {
                    a0 = *reinterpret_cast<const float4*>(&Alds[(rl << 7) | (k0 ^ swr)]);
                    a1 = *reinterpret_cast<const float4*>(&Alds[(rl << 7) | ((k0 + 4) ^ swr)]);
                }
                short8 af;
                af[0] = f2bf(a0.x * sc); af[1] = f2bf(a0.y * sc);
                af[2] = f2bf(a0.z * sc); af[3] = f2bf(a0.w * sc);
                af[4] = f2bf(a1.x * sc); af[5] = f2bf(a1.y * sc);
                af[6] = f2bf(a1.z * sc); af[7] = f2bf(a1.w * sc);
                int gl = ks * 4 + lq;
#pragma unroll
                for (int tt = 0; tt < 8; ++tt) {
                    int feat = tt * 16 + l15;
                    short8 bf_ = *reinterpret_cast<const short8*>(
                        &Wlds[feat * DIM + (kh * 8 + (gl ^ (l15 & 7))) * 8]);
                    acc[tt] = __builtin_amdgcn_mfma_f32_16x16x32_bf16(af, bf_, acc[tt], 0, 0, 0);
                }
            }
        }
        __syncthreads();
    }

    // ---- fused bias + ReLU + LayerNorm epilogue ----
    float bias[8], gm[8], bt[8];
#pragma unroll
    for (int tt = 0; tt < 8; ++tt) {
        bias[tt] = b_self[tt * 16 + l15];
        gm[tt] = gamma[tt * 16 + l15];
        bt[tt] = beta[tt * 16 + l15];
    }
    float s1[4] = {0, 0, 0, 0}, s2[4] = {0, 0, 0, 0};
#pragma unroll
    for (int q = 0; q < 4; ++q)
#pragma unroll
        for (int tt = 0; tt < 8; ++tt) {
            float v = fmaxf(acc[tt][q] + bias[tt], 0.f);
            acc[tt][q] = v;
            s1[q] += v;
            s2[q] += v * v;
        }
#pragma unroll
    for (int m = 1; m < 16; m <<= 1) {
#pragma unroll
        for (int q = 0; q < 4; ++q) {
            s1[q] += __shfl_xor(s1[q], m);
            s2[q] += __shfl_xor(s2[q], m);
        }
    }
#pragma unroll
    for (int q = 0; q < 4; ++q) {
        int grow = b * 64 + w * 16 + lq * 4 + q;
        if (grow < NN) {
            float mean = s1[q] * (1.f / DIM);
            float var = s2[q] * (1.f / DIM) - mean * mean;
            float rst = rsqrtf(var + LN_EPS);
            float* orow = out + (size_t)grow * DIM;
#pragma unroll
            for (int tt = 0; tt < 8; ++tt)
                orow[tt * 16 + l15] = (acc[tt][q] - mean) * rst * gm[tt] + bt[tt];
        }
    }
}

// ---------------------------------------------------------------------------
extern "C" void kernel_launch(void* const* d_in, const int* in_sizes, int n_in,
                              void* d_out, int out_size, void* d_ws, size_t ws_size,
                              hipStream_t stream) {
    const float* h      = (const float*)d_in[0];
    const int*   eidx   = (const int*)d_in[1];
    const int*   etype  = (const int*)d_in[2];
    const float* W_self = (const float*)d_in[3];
    const float* b_self = (const float*)d_in[4];
    const float* W_rel  = (const float*)d_in[5];
    const float* gamma  = (const float*)d_in[6];
    const float* beta   = (const float*)d_in[7];
    float* out = (float*)d_out;

    const int* srcA = eidx;
    const int* dstA = eidx + NE;

    // ws: deg f32[8*NN] | cnt u32[KEYS] | off u32[KEYS+1] | cur u32[KEYS] | ebuf u32[NE]
    float* deg     = (float*)d_ws;
    unsigned* cnt  = (unsigned*)(deg + (size_t)NREL * NN);
    unsigned* off  = cnt + KEYS;
    unsigned* cur  = off + KEYS + 1;
    unsigned* ebuf = cur + KEYS;

    hipMemsetAsync(d_ws, 0, ((size_t)NREL * NN + KEYS) * 4, stream);
    count_kernel<<<(NE + 255) / 256, 256, 0, stream>>>(dstA, etype, deg, cnt);
    scan_kernel<<<1, 1024, 0, stream>>>(cnt, off, cur);
    fill_kernel<<<(NE + 255) / 256, 256, 0, stream>>>(srcA, dstA, etype, cur, ebuf);
    fused_kernel<<<NBUK, 256, 0, stream>>>(out, h, ebuf, off, deg, W_self, W_rel,
                                           b_self, gamma, beta);
}

// Round 8
// 739.136 us; speedup vs baseline: 3.8155x; 1.0448x over previous
//
#include <hip/hip_runtime.h>

#define NN 100000
#define NE 600000
#define DIM 128
#define NREL 8
#define LN_EPS 1e-5f
#define NBUK 1563            // ceil(NN/64)
#define KEYS (NBUK * NREL)   // 12504

typedef __attribute__((ext_vector_type(8))) short short8;
typedef __attribute__((ext_vector_type(4))) float f32x4;

// RNE float -> bf16 (bit pattern in low 16)
static __device__ __forceinline__ short f2bf(float x) {
    unsigned int u = __float_as_uint(x);
    u = (u + 0x7FFFu + ((u >> 16) & 1u)) >> 16;
    return (short)u;
}
static __device__ __forceinline__ float bf2f(unsigned s) {
    return __uint_as_float(s << 16);
}

// ---------------------------------------------------------------------------
// h (f32) -> hb (bf16). Halves the random-gather bytes in fused_kernel.
__global__ __launch_bounds__(256) void conv_h_kernel(const float* __restrict__ h,
                                                     unsigned short* __restrict__ hb) {
    int i = blockIdx.x * 256 + threadIdx.x;  // 8 elements per thread
    if (i < NN * DIM / 8) {
        const float4* p = reinterpret_cast<const float4*>(h + (size_t)i * 8);
        float4 a = p[0], b = p[1];
        short8 o;
        o[0] = f2bf(a.x); o[1] = f2bf(a.y); o[2] = f2bf(a.z); o[3] = f2bf(a.w);
        o[4] = f2bf(b.x); o[5] = f2bf(b.y); o[6] = f2bf(b.z); o[7] = f2bf(b.w);
        *reinterpret_cast<short8*>(hb + (size_t)i * 8) = o;
    }
}

// ---------------------------------------------------------------------------
// W (f32) -> Wb (bf16), pre-arranged in MFMA B-fragment order:
// Wb[((seg*4 + ks)*128 + feat)*32 + (k & 31)],  k = ks*32 + (k&31).
__global__ __launch_bounds__(256) void conv_w_kernel(const float* __restrict__ Ws,
                                                     const float* __restrict__ Wr,
                                                     unsigned short* __restrict__ Wb) {
    int idx = blockIdx.x * 256 + threadIdx.x;
    if (idx < 9 * DIM * DIM) {
        int seg = idx >> 14;
        int rem = idx & 16383;       // i*128 + k
        int i = rem >> 7, k = rem & 127;
        float v = (seg == 0) ? Ws[rem] : Wr[(size_t)(seg - 1) * 16384 + rem];
        Wb[(((size_t)(seg * 4 + (k >> 5)) * DIM + i) << 5) + (k & 31)] =
            (unsigned short)f2bf(v);
    }
}

// ---------------------------------------------------------------------------
// deg[r][n] + cnt[key], key = (dst>>6)*8 + rel.
__global__ __launch_bounds__(256) void count_kernel(const int* __restrict__ dstA,
                                                    const int* __restrict__ etype,
                                                    float* __restrict__ deg,
                                                    unsigned* __restrict__ cnt) {
    int e = blockIdx.x * 256 + threadIdx.x;
    if (e < NE) {
        int d = dstA[e], t = etype[e];
        atomicAdd(&deg[(size_t)t * NN + d], 1.0f);
        atomicAdd(&cnt[(unsigned)(d >> 6) * NREL + (unsigned)t], 1u);
    }
}

// ---------------------------------------------------------------------------
// Single-block exclusive scan of cnt[KEYS] -> off[0..KEYS], cur = copy.
__global__ __launch_bounds__(1024) void scan_kernel(const unsigned* __restrict__ cnt,
                                                    unsigned* __restrict__ off,
                                                    unsigned* __restrict__ cur) {
    __shared__ unsigned buf[KEYS];
    __shared__ unsigned wpart[16];
    int t = threadIdx.x;
    for (int i = t; i < KEYS; i += 1024) buf[i] = cnt[i];
    __syncthreads();
    const int L = 13;
    int base = t * L;
    unsigned s = 0;
    for (int j = 0; j < L; ++j) { int i = base + j; if (i < KEYS) s += buf[i]; }
    unsigned incl = s;
    int lane = t & 63, wid = t >> 6;
    for (int d = 1; d < 64; d <<= 1) {
        unsigned v = __shfl_up(incl, d);
        if (lane >= d) incl += v;
    }
    if (lane == 63) wpart[wid] = incl;
    __syncthreads();
    unsigned wbase = 0;
    for (int q = 0; q < wid; ++q) wbase += wpart[q];
    unsigned run = wbase + incl - s;
    for (int j = 0; j < L; ++j) {
        int i = base + j;
        if (i < KEYS) { unsigned c = buf[i]; off[i] = run; cur[i] = run; run += c; }
    }
    if (t == 1023) off[KEYS] = wbase + incl;
}

// ---------------------------------------------------------------------------
// Fill sorted edge buffer. rec = src | dl<<17 | rel<<23.
__global__ __launch_bounds__(256) void fill_kernel(const int* __restrict__ srcA,
                                                   const int* __restrict__ dstA,
                                                   const int* __restrict__ etype,
                                                   unsigned* __restrict__ cur,
                                                   unsigned* __restrict__ ebuf) {
    int e = blockIdx.x * 256 + threadIdx.x;
    if (e < NE) {
        int d = dstA[e], s = srcA[e], t = etype[e];
        unsigned k = (unsigned)(d >> 6) * NREL + (unsigned)t;
        unsigned pos = atomicAdd(&cur[k], 1u);
        ebuf[pos] = (unsigned)s | ((unsigned)(d & 63) << 17) | ((unsigned)t << 23);
    }
}

// ---------------------------------------------------------------------------
// Fused per-bucket kernel. 64 rows/block, 4 waves tiling the FEATURE dim
// (wave w owns feats [w*32, w*32+32), all 64 rows). A aggregated in LDS
// (swizzled f32, ds atomics, 1/deg folded in), W fragments read directly
// from L2-resident pre-swizzled Wb. 32KB Alds -> 4 blocks/CU.
__global__ __launch_bounds__(256, 4) void fused_kernel(
    float* __restrict__ out, const unsigned short* __restrict__ hb,
    const unsigned short* __restrict__ Wb, const unsigned* __restrict__ ebuf,
    const unsigned* __restrict__ off, const float* __restrict__ deg,
    const float* __restrict__ b_self, const float* __restrict__ gamma,
    const float* __restrict__ beta) {
    __shared__ float Alds[64 * DIM];   // 32 KB, word = (row<<7) | (k ^ ((row&7)<<2))
    __shared__ float invd[NREL * 64];  // 2 KB
    __shared__ float P1[4 * 64], P2[4 * 64], MR[2 * 64];

    const int t = threadIdx.x;
    const int w = t >> 6, l = t & 63;
    const int l15 = l & 15, lq = l >> 4;
    const int b = blockIdx.x;
    const int qw = t >> 4, j16 = t & 15;  // quarter-wave id / lane-in-quarter
    const int swr = (l15 & 7) << 2;

    // per-block 1/max(deg,1) table
    for (int i = t; i < NREL * 64; i += 256) {
        int r = i >> 6, row = i & 63, g = b * 64 + row;
        float d = (g < NN) ? deg[(size_t)r * NN + g] : 1.f;
        invd[i] = 1.f / fmaxf(d, 1.f);
    }

    f32x4 acc[4][2];  // [row-group][feat-tile]
#pragma unroll
    for (int i = 0; i < 4; ++i) { acc[i][0] = (f32x4)(0.f); acc[i][1] = (f32x4)(0.f); }

    // ---- seg 0: self term, A direct from hb ----
#pragma unroll
    for (int ks = 0; ks < 4; ++ks) {
        short8 bfr0 = *reinterpret_cast<const short8*>(
            Wb + (((size_t)(0 * 4 + ks) * DIM + w * 32 + l15) << 5) + lq * 8);
        short8 bfr1 = *reinterpret_cast<const short8*>(
            Wb + (((size_t)(0 * 4 + ks) * DIM + w * 32 + 16 + l15) << 5) + lq * 8);
#pragma unroll
        for (int rg = 0; rg < 4; ++rg) {
            int row = b * 64 + rg * 16 + l15;
            if (row >= NN) row = NN - 1;
            short8 af = *reinterpret_cast<const short8*>(
                hb + (size_t)row * DIM + ks * 32 + lq * 8);
            acc[rg][0] = __builtin_amdgcn_mfma_f32_16x16x32_bf16(af, bfr0, acc[rg][0], 0, 0, 0);
            acc[rg][1] = __builtin_amdgcn_mfma_f32_16x16x32_bf16(af, bfr1, acc[rg][1], 0, 0, 0);
        }
    }
    __syncthreads();  // invd ready; Alds about to be used

    for (int r = 0; r < NREL; ++r) {
        // ---- zero A ----
        {
            float4 z = make_float4(0.f, 0.f, 0.f, 0.f);
            float4* A4 = reinterpret_cast<float4*>(Alds);
#pragma unroll
            for (int i = 0; i < 8; ++i) A4[t + i * 256] = z;
        }
        __syncthreads();
        // ---- aggregate rel r: quarter-wave per edge, 2-deep pipelined ----
        {
            unsigned o0 = off[(unsigned)b * NREL + r];
            unsigned o1 = off[(unsigned)b * NREL + r + 1];
            unsigned u = o0 + qw;
            bool act = u < o1;
            unsigned rec = act ? ebuf[u] : 0u;
            uint4 hv = make_uint4(0u, 0u, 0u, 0u);
            if (act)
                hv = *reinterpret_cast<const uint4*>(
                    hb + (size_t)(rec & 0x1FFFFu) * DIM + j16 * 8);
            while (act) {
                unsigned un = u + 16;
                bool actn = un < o1;
                unsigned recn = actn ? ebuf[un] : 0u;
                uint4 hvn = make_uint4(0u, 0u, 0u, 0u);
                if (actn)
                    hvn = *reinterpret_cast<const uint4*>(
                        hb + (size_t)(recn & 0x1FFFFu) * DIM + j16 * 8);
                int dl = (int)((rec >> 17) & 63u);
                float iv = invd[r * 64 + dl];
                int base = dl << 7;
                int sw = (dl & 7) << 2;
                int k = j16 * 8;
                atomicAdd(&Alds[base | ((k + 0) ^ sw)], bf2f(hv.x & 0xFFFFu) * iv);
                atomicAdd(&Alds[base | ((k + 1) ^ sw)], bf2f(hv.x >> 16) * iv);
                atomicAdd(&Alds[base | ((k + 2) ^ sw)], bf2f(hv.y & 0xFFFFu) * iv);
                atomicAdd(&Alds[base | ((k + 3) ^ sw)], bf2f(hv.y >> 16) * iv);
                atomicAdd(&Alds[base | ((k + 4) ^ sw)], bf2f(hv.z & 0xFFFFu) * iv);
                atomicAdd(&Alds[base | ((k + 5) ^ sw)], bf2f(hv.z >> 16) * iv);
                atomicAdd(&Alds[base | ((k + 6) ^ sw)], bf2f(hv.w & 0xFFFFu) * iv);
                atomicAdd(&Alds[base | ((k + 7) ^ sw)], bf2f(hv.w >> 16) * iv);
                u = un; act = actn; rec = recn; hv = hvn;
            }
        }
        __syncthreads();
        // ---- MFMA this relation's 128-K segment ----
        const int seg = r + 1;
#pragma unroll
        for (int ks = 0; ks < 4; ++ks) {
            short8 bfr0 = *reinterpret_cast<const short8*>(
                Wb + (((size_t)(seg * 4 + ks) * DIM + w * 32 + l15) << 5) + lq * 8);
            short8 bfr1 = *reinterpret_cast<const short8*>(
                Wb + (((size_t)(seg * 4 + ks) * DIM + w * 32 + 16 + l15) << 5) + lq * 8);
#pragma unroll
            for (int rg = 0; rg < 4; ++rg) {
                int arow = rg * 16 + l15;
                int k0 = ks * 32 + lq * 8;
                float4 a0 = *reinterpret_cast<const float4*>(&Alds[(arow << 7) | (k0 ^ swr)]);
                float4 a1 = *reinterpret_cast<const float4*>(&Alds[(arow << 7) | ((k0 + 4) ^ swr)]);
                short8 af;
                af[0] = f2bf(a0.x); af[1] = f2bf(a0.y); af[2] = f2bf(a0.z); af[3] = f2bf(a0.w);
                af[4] = f2bf(a1.x); af[5] = f2bf(a1.y); af[6] = f2bf(a1.z); af[7] = f2bf(a1.w);
                acc[rg][0] = __builtin_amdgcn_mfma_f32_16x16x32_bf16(af, bfr0, acc[rg][0], 0, 0, 0);
                acc[rg][1] = __builtin_amdgcn_mfma_f32_16x16x32_bf16(af, bfr1, acc[rg][1], 0, 0, 0);
            }
        }
        __syncthreads();  // before next zero
    }

    // ---- epilogue: bias + ReLU, cross-wave LN reduce, store ----
    float bi0 = b_self[w * 32 + l15], bi1 = b_self[w * 32 + 16 + l15];
    float g0 = gamma[w * 32 + l15], g1 = gamma[w * 32 + 16 + l15];
    float be0 = beta[w * 32 + l15], be1 = beta[w * 32 + 16 + l15];
#pragma unroll
    for (int rg = 0; rg < 4; ++rg)
#pragma unroll
        for (int q = 0; q < 4; ++q) {
            float v0 = fmaxf(acc[rg][0][q] + bi0, 0.f);
            float v1 = fmaxf(acc[rg][1][q] + bi1, 0.f);
            acc[rg][0][q] = v0;
            acc[rg][1][q] = v1;
            float s1 = v0 + v1, s2 = v0 * v0 + v1 * v1;
#pragma unroll
            for (int m = 1; m < 16; m <<= 1) {
                s1 += __shfl_xor(s1, m);
                s2 += __shfl_xor(s2, m);
            }
            int row = rg * 16 + lq * 4 + q;
            if (l15 == 0) { P1[w * 64 + row] = s1; P2[w * 64 + row] = s2; }
        }
    __syncthreads();
    if (t < 64) {
        float s1 = P1[t] + P1[64 + t] + P1[128 + t] + P1[192 + t];
        float s2 = P2[t] + P2[64 + t] + P2[128 + t] + P2[192 + t];
        float mean = s1 * (1.f / DIM);
        float var = s2 * (1.f / DIM) - mean * mean;
        MR[t] = mean;
        MR[64 + t] = rsqrtf(var + LN_EPS);
    }
    __syncthreads();
#pragma unroll
    for (int rg = 0; rg < 4; ++rg)
#pragma unroll
        for (int q = 0; q < 4; ++q) {
            int row = rg * 16 + lq * 4 + q;
            int grow = b * 64 + row;
            if (grow < NN) {
                float mean = MR[row], rstd = MR[64 + row];
                float* orow = out + (size_t)grow * DIM + w * 32;
                orow[l15] = (acc[rg][0][q] - mean) * rstd * g0 + be0;
                orow[16 + l15] = (acc[rg][1][q] - mean) * rstd * g1 + be1;
            }
        }
}

// ---------------------------------------------------------------------------
extern "C" void kernel_launch(void* const* d_in, const int* in_sizes, int n_in,
                              void* d_out, int out_size, void* d_ws, size_t ws_size,
                              hipStream_t stream) {
    const float* h      = (const float*)d_in[0];
    const int*   eidx   = (const int*)d_in[1];
    const int*   etype  = (const int*)d_in[2];
    const float* W_self = (const float*)d_in[3];
    const float* b_self = (const float*)d_in[4];
    const float* W_rel  = (const float*)d_in[5];
    const float* gamma  = (const float*)d_in[6];
    const float* beta   = (const float*)d_in[7];
    float* out = (float*)d_out;

    const int* srcA = eidx;
    const int* dstA = eidx + NE;

    // ws: hb bf16[NN*128] | Wb bf16[9*128*128] | deg f32[8*NN] | cnt | off | cur | ebuf
    unsigned short* hb = (unsigned short*)d_ws;
    unsigned short* Wb = hb + (size_t)NN * DIM;
    float* deg     = (float*)(Wb + 9 * DIM * DIM);
    unsigned* cnt  = (unsigned*)(deg + (size_t)NREL * NN);
    unsigned* off  = cnt + KEYS;
    unsigned* cur  = off + KEYS + 1;
    unsigned* ebuf = cur + KEYS;

    conv_h_kernel<<<(NN * DIM / 8 + 255) / 256, 256, 0, stream>>>(h, hb);
    conv_w_kernel<<<(9 * DIM * DIM + 255) / 256, 256, 0, stream>>>(W_self, W_rel, Wb);
    hipMemsetAsync(deg, 0, ((size_t)NREL * NN + KEYS) * 4, stream);
    count_kernel<<<(NE + 255) / 256, 256, 0, stream>>>(dstA, etype, deg, cnt);
    scan_kernel<<<1, 1024, 0, stream>>>(cnt, off, cur);
    fill_kernel<<<(NE + 255) / 256, 256, 0, stream>>>(srcA, dstA, etype, cur, ebuf);
    fused_kernel<<<NBUK, 256, 0, stream>>>(out, hb, Wb, ebuf, off, deg, b_self,
                                           gamma, beta);
}

// Round 9
// 316.131 us; speedup vs baseline: 8.9209x; 2.3381x over previous
//
#include <hip/hip_runtime.h>

#define NN 100000
#define NE 600000
#define DIM 128
#define NREL 8
#define LN_EPS 1e-5f
#define NBUK 1563               // ceil(NN/64)
#define KEYS2 (NN * NREL)       // 800000 keys: dst*8+rel
#define NSB ((KEYS2 + 1023) / 1024)  // 782 scan blocks

typedef __attribute__((ext_vector_type(8))) short short8;
typedef __attribute__((ext_vector_type(4))) float f32x4;

static __device__ __forceinline__ short f2bf(float x) {
    unsigned int u = __float_as_uint(x);
    u = (u + 0x7FFFu + ((u >> 16) & 1u)) >> 16;
    return (short)u;
}
static __device__ __forceinline__ float bf2f(unsigned s) {
    return __uint_as_float(s << 16);
}

// ---------------------------------------------------------------------------
__global__ __launch_bounds__(256) void conv_h_kernel(const float* __restrict__ h,
                                                     unsigned short* __restrict__ hb) {
    int i = blockIdx.x * 256 + threadIdx.x;
    if (i < NN * DIM / 8) {
        const float4* p = reinterpret_cast<const float4*>(h + (size_t)i * 8);
        float4 a = p[0], b = p[1];
        short8 o;
        o[0] = f2bf(a.x); o[1] = f2bf(a.y); o[2] = f2bf(a.z); o[3] = f2bf(a.w);
        o[4] = f2bf(b.x); o[5] = f2bf(b.y); o[6] = f2bf(b.z); o[7] = f2bf(b.w);
        *reinterpret_cast<short8*>(hb + (size_t)i * 8) = o;
    }
}

// W -> bf16 in MFMA B-fragment order: Wb[((seg*4+ks)*128 + feat)*32 + (k&31)]
__global__ __launch_bounds__(256) void conv_w_kernel(const float* __restrict__ Ws,
                                                     const float* __restrict__ Wr,
                                                     unsigned short* __restrict__ Wb) {
    int idx = blockIdx.x * 256 + threadIdx.x;
    if (idx < 9 * DIM * DIM) {
        int seg = idx >> 14;
        int rem = idx & 16383;
        int i = rem >> 7, k = rem & 127;
        float v = (seg == 0) ? Ws[rem] : Wr[(size_t)(seg - 1) * 16384 + rem];
        Wb[(((size_t)(seg * 4 + (k >> 5)) * DIM + i) << 5) + (k & 31)] =
            (unsigned short)f2bf(v);
    }
}

// ---------------------------------------------------------------------------
__global__ __launch_bounds__(256) void count_kernel(const int* __restrict__ dstA,
                                                    const int* __restrict__ etype,
                                                    unsigned* __restrict__ cnt) {
    int e = blockIdx.x * 256 + threadIdx.x;
    if (e < NE)
        atomicAdd(&cnt[(unsigned)dstA[e] * NREL + (unsigned)etype[e]], 1u);
}

// ---- 3-phase exclusive scan of cnt[KEYS2] -> off, cur ----
__global__ __launch_bounds__(1024) void scan1_kernel(const unsigned* __restrict__ cnt,
                                                     unsigned* __restrict__ off,
                                                     unsigned* __restrict__ bsum) {
    __shared__ unsigned wpart[16];
    int i = blockIdx.x * 1024 + threadIdx.x;
    unsigned v = (i < KEYS2) ? cnt[i] : 0u;
    unsigned incl = v;
    int lane = threadIdx.x & 63, wid = threadIdx.x >> 6;
    for (int d = 1; d < 64; d <<= 1) {
        unsigned u = __shfl_up(incl, d);
        if (lane >= d) incl += u;
    }
    if (lane == 63) wpart[wid] = incl;
    __syncthreads();
    unsigned wbase = 0;
    for (int q = 0; q < wid; ++q) wbase += wpart[q];
    if (i < KEYS2) off[i] = wbase + incl - v;
    if (threadIdx.x == 1023) bsum[blockIdx.x] = wbase + incl;
}

__global__ __launch_bounds__(1024) void scan2_kernel(const unsigned* __restrict__ bsum,
                                                     unsigned* __restrict__ bpre,
                                                     unsigned* __restrict__ off) {
    __shared__ unsigned wpart[16];
    int t = threadIdx.x;
    unsigned v = (t < NSB) ? bsum[t] : 0u;
    unsigned incl = v;
    int lane = t & 63, wid = t >> 6;
    for (int d = 1; d < 64; d <<= 1) {
        unsigned u = __shfl_up(incl, d);
        if (lane >= d) incl += u;
    }
    if (lane == 63) wpart[wid] = incl;
    __syncthreads();
    unsigned wbase = 0;
    for (int q = 0; q < wid; ++q) wbase += wpart[q];
    if (t < NSB) bpre[t] = wbase + incl - v;
    if (t == 0) off[KEYS2] = NE;
}

__global__ __launch_bounds__(1024) void scan3_kernel(unsigned* __restrict__ off,
                                                     const unsigned* __restrict__ bpre,
                                                     unsigned* __restrict__ cur) {
    int i = blockIdx.x * 1024 + threadIdx.x;
    if (i < KEYS2) {
        unsigned v = off[i] + bpre[i >> 10];
        off[i] = v;
        cur[i] = v;
    }
}

// ---------------------------------------------------------------------------
__global__ __launch_bounds__(256) void fill_kernel(const int* __restrict__ srcA,
                                                   const int* __restrict__ dstA,
                                                   const int* __restrict__ etype,
                                                   unsigned* __restrict__ cur,
                                                   unsigned* __restrict__ ebuf) {
    int e = blockIdx.x * 256 + threadIdx.x;
    if (e < NE) {
        unsigned k = (unsigned)dstA[e] * NREL + (unsigned)etype[e];
        unsigned pos = atomicAdd(&cur[k], 1u);
        ebuf[pos] = (unsigned)srcA[e];
    }
}

// ---------------------------------------------------------------------------
// Fused per-bucket kernel, CSR gather-sum. 64 rows/block, 4 waves on feature
// dim. Quarter-wave owns 4 rows: batch-gather first edges (4 in flight),
// register-sum f32, scale 1/deg, ONE plain swizzled LDS write per row.
// No LDS atomics, no zeroing pass. MFMA reads Alds + L2-resident Wb.
__global__ __launch_bounds__(256, 4) void fused_kernel(
    float* __restrict__ out, const unsigned short* __restrict__ hb,
    const unsigned short* __restrict__ Wb, const unsigned* __restrict__ ebuf,
    const unsigned* __restrict__ off, const float* __restrict__ b_self,
    const float* __restrict__ gamma, const float* __restrict__ beta) {
    __shared__ float Alds[64 * DIM];   // 32 KB; word = (row<<7) | (k ^ ((row&7)<<2))
    __shared__ unsigned offs[520];     // CSR offsets for this bucket (513 used)
    __shared__ float P1[256], P2[256], MR[128];

    const int t = threadIdx.x;
    const int w = t >> 6, l = t & 63;
    const int l15 = l & 15, lq = l >> 4;
    const int b = blockIdx.x;
    const int qw = t >> 4, j16 = t & 15;
    const int swr = (l15 & 7) << 2;

    // stage this bucket's 513 CSR offsets (keys b*512 .. b*512+512, clamped)
    for (int i = t; i < 513; i += 256) {
        int idx = b * 512 + i;
        offs[i] = off[idx > KEYS2 ? KEYS2 : idx];
    }

    f32x4 acc[4][2];
#pragma unroll
    for (int i = 0; i < 4; ++i) { acc[i][0] = (f32x4)(0.f); acc[i][1] = (f32x4)(0.f); }

    // ---- seg 0: self term straight from hb ----
#pragma unroll
    for (int ks = 0; ks < 4; ++ks) {
        short8 bfr0 = *reinterpret_cast<const short8*>(
            Wb + (((size_t)ks * DIM + w * 32 + l15) << 5) + lq * 8);
        short8 bfr1 = *reinterpret_cast<const short8*>(
            Wb + (((size_t)ks * DIM + w * 32 + 16 + l15) << 5) + lq * 8);
#pragma unroll
        for (int rg = 0; rg < 4; ++rg) {
            int row = b * 64 + rg * 16 + l15;
            if (row >= NN) row = NN - 1;
            short8 af = *reinterpret_cast<const short8*>(
                hb + (size_t)row * DIM + ks * 32 + lq * 8);
            acc[rg][0] = __builtin_amdgcn_mfma_f32_16x16x32_bf16(af, bfr0, acc[rg][0], 0, 0, 0);
            acc[rg][1] = __builtin_amdgcn_mfma_f32_16x16x32_bf16(af, bfr1, acc[rg][1], 0, 0, 0);
        }
    }
    __syncthreads();  // offs visible

    for (int r = 0; r < NREL; ++r) {
        // ---- CSR aggregate: rows qw*4 .. qw*4+3 ----
        const int row0 = qw * 4;
        unsigned o0[4], c[4];
#pragma unroll
        for (int rr = 0; rr < 4; ++rr) {
            unsigned a = offs[(row0 + rr) * NREL + r];
            unsigned e = offs[(row0 + rr) * NREL + r + 1];
            o0[rr] = a;
            c[rr] = e - a;
        }
        unsigned s4[4];
#pragma unroll
        for (int rr = 0; rr < 4; ++rr) s4[rr] = c[rr] ? ebuf[o0[rr]] : 0u;
        uint4 g[4];
#pragma unroll
        for (int rr = 0; rr < 4; ++rr)
            g[rr] = c[rr] ? *reinterpret_cast<const uint4*>(
                                hb + (size_t)s4[rr] * DIM + j16 * 8)
                          : make_uint4(0u, 0u, 0u, 0u);
#pragma unroll
        for (int pp = 0; pp < 2; ++pp) {
            float sm[2][8];
#pragma unroll
            for (int q2 = 0; q2 < 2; ++q2) {
                const int rr = pp * 2 + q2;
                uint4 gv = g[rr];
                sm[q2][0] = bf2f(gv.x & 0xFFFFu); sm[q2][1] = bf2f(gv.x >> 16);
                sm[q2][2] = bf2f(gv.y & 0xFFFFu); sm[q2][3] = bf2f(gv.y >> 16);
                sm[q2][4] = bf2f(gv.z & 0xFFFFu); sm[q2][5] = bf2f(gv.z >> 16);
                sm[q2][6] = bf2f(gv.w & 0xFFFFu); sm[q2][7] = bf2f(gv.w >> 16);
                for (unsigned u = 1; u < c[rr]; ++u) {  // rare (deg mean 0.75)
                    unsigned s = ebuf[o0[rr] + u];
                    uint4 gg = *reinterpret_cast<const uint4*>(
                        hb + (size_t)s * DIM + j16 * 8);
                    sm[q2][0] += bf2f(gg.x & 0xFFFFu); sm[q2][1] += bf2f(gg.x >> 16);
                    sm[q2][2] += bf2f(gg.y & 0xFFFFu); sm[q2][3] += bf2f(gg.y >> 16);
                    sm[q2][4] += bf2f(gg.z & 0xFFFFu); sm[q2][5] += bf2f(gg.z >> 16);
                    sm[q2][6] += bf2f(gg.w & 0xFFFFu); sm[q2][7] += bf2f(gg.w >> 16);
                }
                const int row = row0 + rr;
                float iv = 1.f / fmaxf((float)c[rr], 1.f);
                int sw = (row & 7) << 2;
                int b0w = (row << 7) | ((j16 * 8) ^ (sw & 24));
                float4 lo = make_float4(sm[q2][0] * iv, sm[q2][1] * iv,
                                        sm[q2][2] * iv, sm[q2][3] * iv);
                float4 hi = make_float4(sm[q2][4] * iv, sm[q2][5] * iv,
                                        sm[q2][6] * iv, sm[q2][7] * iv);
                if (sw & 4) { float4 tmp = lo; lo = hi; hi = tmp; }
                *reinterpret_cast<float4*>(&Alds[b0w]) = lo;
                *reinterpret_cast<float4*>(&Alds[b0w + 4]) = hi;
            }
        }
        __syncthreads();
        // ---- MFMA this relation's 128-K segment ----
        const int seg = r + 1;
#pragma unroll
        for (int ks = 0; ks < 4; ++ks) {
            short8 bfr0 = *reinterpret_cast<const short8*>(
                Wb + (((size_t)(seg * 4 + ks) * DIM + w * 32 + l15) << 5) + lq * 8);
            short8 bfr1 = *reinterpret_cast<const short8*>(
                Wb + (((size_t)(seg * 4 + ks) * DIM + w * 32 + 16 + l15) << 5) + lq * 8);
#pragma unroll
            for (int rg = 0; rg < 4; ++rg) {
                int arow = rg * 16 + l15;
                int k0 = ks * 32 + lq * 8;
                float4 a0 = *reinterpret_cast<const float4*>(&Alds[(arow << 7) | (k0 ^ swr)]);
                float4 a1 = *reinterpret_cast<const float4*>(&Alds[(arow << 7) | ((k0 + 4) ^ swr)]);
                short8 af;
                af[0] = f2bf(a0.x); af[1] = f2bf(a0.y); af[2] = f2bf(a0.z); af[3] = f2bf(a0.w);
                af[4] = f2bf(a1.x); af[5] = f2bf(a1.y); af[6] = f2bf(a1.z); af[7] = f2bf(a1.w);
                acc[rg][0] = __builtin_amdgcn_mfma_f32_16x16x32_bf16(af, bfr0, acc[rg][0], 0, 0, 0);
                acc[rg][1] = __builtin_amdgcn_mfma_f32_16x16x32_bf16(af, bfr1, acc[rg][1], 0, 0, 0);
            }
        }
        __syncthreads();
    }

    // ---- epilogue: bias + ReLU, cross-wave LN reduce, store ----
    float bi0 = b_self[w * 32 + l15], bi1 = b_self[w * 32 + 16 + l15];
    float g0 = gamma[w * 32 + l15], g1 = gamma[w * 32 + 16 + l15];
    float be0 = beta[w * 32 + l15], be1 = beta[w * 32 + 16 + l15];
#pragma unroll
    for (int rg = 0; rg < 4; ++rg)
#pragma unroll
        for (int q = 0; q < 4; ++q) {
            float v0 = fmaxf(acc[rg][0][q] + bi0, 0.f);
            float v1 = fmaxf(acc[rg][1][q] + bi1, 0.f);
            acc[rg][0][q] = v0;
            acc[rg][1][q] = v1;
            float s1 = v0 + v1, s2 = v0 * v0 + v1 * v1;
#pragma unroll
            for (int m = 1; m < 16; m <<= 1) {
                s1 += __shfl_xor(s1, m);
                s2 += __shfl_xor(s2, m);
            }
            int row = rg * 16 + lq * 4 + q;
            if (l15 == 0) { P1[w * 64 + row] = s1; P2[w * 64 + row] = s2; }
        }
    __syncthreads();
    if (t < 64) {
        float s1 = P1[t] + P1[64 + t] + P1[128 + t] + P1[192 + t];
        float s2 = P2[t] + P2[64 + t] + P2[128 + t] + P2[192 + t];
        float mean = s1 * (1.f / DIM);
        float var = s2 * (1.f / DIM) - mean * mean;
        MR[t] = mean;
        MR[64 + t] = rsqrtf(var + LN_EPS);
    }
    __syncthreads();
#pragma unroll
    for (int rg = 0; rg < 4; ++rg)
#pragma unroll
        for (int q = 0; q < 4; ++q) {
            int row = rg * 16 + lq * 4 + q;
            int grow = b * 64 + row;
            if (grow < NN) {
                float mean = MR[row], rstd = MR[64 + row];
                float* orow = out + (size_t)grow * DIM + w * 32;
                orow[l15] = (acc[rg][0][q] - mean) * rstd * g0 + be0;
                orow[16 + l15] = (acc[rg][1][q] - mean) * rstd * g1 + be1;
            }
        }
}

// ---------------------------------------------------------------------------
extern "C" void kernel_launch(void* const* d_in, const int* in_sizes, int n_in,
                              void* d_out, int out_size, void* d_ws, size_t ws_size,
                              hipStream_t stream) {
    const float* h      = (const float*)d_in[0];
    const int*   eidx   = (const int*)d_in[1];
    const int*   etype  = (const int*)d_in[2];
    const float* W_self = (const float*)d_in[3];
    const float* b_self = (const float*)d_in[4];
    const float* W_rel  = (const float*)d_in[5];
    const float* gamma  = (const float*)d_in[6];
    const float* beta   = (const float*)d_in[7];
    float* out = (float*)d_out;

    const int* srcA = eidx;
    const int* dstA = eidx + NE;

    // ws: hb bf16[NN*128] | Wb bf16[9*16384] | cnt u32[KEYS2] | off u32[KEYS2+1]
    //     | cur u32[KEYS2] | bsum u32[NSB] | bpre u32[NSB] | ebuf u32[NE]
    unsigned short* hb = (unsigned short*)d_ws;
    unsigned short* Wb = hb + (size_t)NN * DIM;
    unsigned* cnt  = (unsigned*)(Wb + 9 * DIM * DIM);
    unsigned* off  = cnt + KEYS2;
    unsigned* cur  = off + KEYS2 + 1;
    unsigned* bsum = cur + KEYS2;
    unsigned* bpre = bsum + NSB;
    unsigned* ebuf = bpre + NSB;

    conv_h_kernel<<<(NN * DIM / 8 + 255) / 256, 256, 0, stream>>>(h, hb);
    conv_w_kernel<<<(9 * DIM * DIM + 255) / 256, 256, 0, stream>>>(W_self, W_rel, Wb);
    hipMemsetAsync(cnt, 0, (size_t)KEYS2 * 4, stream);
    count_kernel<<<(NE + 255) / 256, 256, 0, stream>>>(dstA, etype, cnt);
    scan1_kernel<<<NSB, 1024, 0, stream>>>(cnt, off, bsum);
    scan2_kernel<<<1, 1024, 0, stream>>>(bsum, bpre, off);
    scan3_kernel<<<NSB, 1024, 0, stream>>>(off, bpre, cur);
    fill_kernel<<<(NE + 255) / 256, 256, 0, stream>>>(srcA, dstA, etype, cur, ebuf);
    fused_kernel<<<NBUK, 256, 0, stream>>>(out, hb, Wb, ebuf, off, b_self, gamma, beta);
}